// Round 11
// baseline (120.284 us; speedup 1.0000x reference)
//
#include <hip/hip_runtime.h>
#include <math.h>

// QLSTM fused single-kernel version.
//
// qgate(x,p)[b,w] = prod_{j<=w} cos(p[j,1]) * cos(p[j,0] + x[b,j])
//
// Round 16 (this session): phase-1 gw-split + two chain-depth trims.
//  (a) 1024 threads (16 waves): thread (tt = tid&127, grp = tid>>7) computes
//      5 FULL 64-elem dots (gw = grp*5..+5): 320 serial FMAs/thread vs R15's
//      1280+combine; NO partials LDS (each thread writes its own Zl rows);
//      full-dot fma order restored (Z bitwise = R13/R8). x-row loads are 8x
//      redundant but L1-served. LDS ~37 KB.
//  (b) Estrin gate poly: qp = fmaf(y^2, fmaf(y,qd,qc), fmaf(y,qb,qa)) --
//      depth 4 vs 5 after prod.
//  (c) cc-tanh rcp overlap: on = O_*num during rcp(den) flight; hraw =
//      fmaf(on, rd, hn) -- 1 hop after rcp instead of 2.
// Recurrence otherwise identical to R15 (dur 119.2; kernel no longer in
// top-5, i.e. <40 us).

#define T_STEPS 128
#define B_SZ    256
#define D_IN    64
#define H_SZ    10
#define COMB    74   // D_IN + H_SZ
#define ZPAD    132  // Z row stride (floats); 132*4=528 B keeps b128 16B-aligned

#define INV2PI  0.15915494f

__device__ __forceinline__ float rdlane(float v, int lane) {
    return __int_as_float(__builtin_amdgcn_readlane(__float_as_int(v), lane));
}
__device__ __forceinline__ float frcp(float x) { return __builtin_amdgcn_rcpf(x); }

__global__ __launch_bounds__(1024) void qlstm_fused(
    const float* __restrict__ x,
    const float* __restrict__ Wf, const float* __restrict__ bf, const float* __restrict__ pf,
    const float* __restrict__ Wi, const float* __restrict__ bi, const float* __restrict__ pi,
    const float* __restrict__ Wu, const float* __restrict__ bu, const float* __restrict__ pu,
    const float* __restrict__ Wo, const float* __restrict__ bo, const float* __restrict__ po,
    const float* __restrict__ ln_g, const float* __restrict__ ln_b,
    float* __restrict__ ys, float* __restrict__ outH, float* __restrict__ outC)
{
    __shared__ __align__(16) float Wl[40 * 64];               // 10.0 KB
    __shared__ __align__(16) float Zl[40 * ZPAD];             // 21.1 KB
    __shared__ __align__(16) float ys_l[T_STEPS * H_SZ + 64]; // 5.4 KB
    __shared__ float bl[40];
    __shared__ float p0l[40];
    // total ~37 KB

    const int tid = threadIdx.x;   // 0..1023
    const int grp = tid >> 7;      // gw-group 0..7 (5 gate-wires each)
    const int tt  = tid & 127;     // t-row owner in phase 1
    const int b   = blockIdx.x;    // batch

    // ---- phase 0: full x-row (64 floats) into regs (8x redundant, L1) ------
    float xr[64];
    const float4* xin = (const float4*)(x + ((size_t)tt * B_SZ + b) * D_IN);
#pragma unroll
    for (int k = 0; k < 16; k++) {
        float4 v = xin[k];
        xr[4*k+0] = v.x; xr[4*k+1] = v.y; xr[4*k+2] = v.z; xr[4*k+3] = v.w;
    }

    // ---- stage W,b,p0 into LDS (r wave-uniform -> scalar branches) ---------
#pragma unroll
    for (int k = 0; k < 3; k++) {
        int idx = k * 1024 + tid;
        if (idx < 2560) {                  // wave-uniform guard (k=2: waves 0-7)
            int r   = idx >> 6;            // row 0..39, uniform within each wave
            int col = idx & 63;
            const float* Wp; int w;
            if      (r < 10) { Wp = Wf; w = r;      }
            else if (r < 20) { Wp = Wi; w = r - 10; }
            else if (r < 30) { Wp = Wu; w = r - 20; }
            else             { Wp = Wo; w = r - 30; }
            Wl[idx] = Wp[w * COMB + col];
        }
    }
    if (tid < 40) {
        int r = tid;
        const float* bp; const float* pp; int w;
        if      (r < 10) { bp = bf; pp = pf; w = r;      }
        else if (r < 20) { bp = bi; pp = pi; w = r - 10; }
        else if (r < 30) { bp = bu; pp = pu; w = r - 20; }
        else             { bp = bo; pp = po; w = r - 30; }
        bl[tid]  = bp[w];
        p0l[tid] = pp[w * 3];
    }
    __syncthreads();

    // ---- phase 1: 5 full dots per thread (gw = grp*5 + i), original order --
#pragma unroll
    for (int i = 0; i < 5; i++) {
        const int gw = grp * 5 + i;
        float a = bl[gw];
        const float4* wr4 = (const float4*)(Wl + gw * 64);  // uniform b128
#pragma unroll
        for (int d4 = 0; d4 < 16; d4++) {
            float4 wv = wr4[d4];
            a = fmaf(xr[4*d4+0], wv.x, a);
            a = fmaf(xr[4*d4+1], wv.y, a);
            a = fmaf(xr[4*d4+2], wv.z, a);
            a = fmaf(xr[4*d4+3], wv.w, a);
        }
        Zl[gw * ZPAD + tt] = (a + p0l[gw]) * INV2PI;   // revolution domain
    }
    __syncthreads();

    if (tid >= 64) return;         // waves 1-15 done; wave 0 runs the recurrence

    // ---- phase 2: sequential recurrence ------------------------------------
    const int lane = tid;
    const int g    = lane >> 4;        // gate 0..3 = f,i,u,o
    const int w    = lane & 15;        // wire 0..15 (10 active)
    const bool act = (w < H_SZ);

    const float* Ws[4] = {Wf, Wi, Wu, Wo};
    const float* ps[4] = {pf, pi, pu, po};

    // LN folded into the recurrence, REV-DOMAIN scaled:
    //   htr = hterm/2pi = rstd*(sum_j whp'[j]*hraw[j] - mu*S) + A
    float whp[H_SZ];
    float S = 0.f, A = 0.f;
#pragma unroll
    for (int j = 0; j < H_SZ; j++) {
        float whj = act ? Ws[g][w * COMB + D_IN + j] : 0.f;
        whp[j] = whj * ln_g[j] * INV2PI;
        S += whp[j];
        A  = fmaf(whj, ln_b[j], A);
    }
    A *= INV2PI;

    const float cp1 = act ? __cosf(ps[g][w * 3 + 1]) : 1.f;
    const float lng = act ? ln_g[w] : 0.f;
    const float lnb = act ? ln_b[w] : 0.f;
    // gate u (g==2): tanh(q); others: sigmoid(q) = 0.5 + 0.5*tanh(q/2)
    const float s1 = (g == 2) ? 1.f : 0.5f;
    const float sc = (g == 2) ? 1.f : 0.5f;
    const float s0l = (act ? ((g == 2) ? 0.f : 0.5f) : 0.f);

    // cpp = prefix product of cp1 within the 16-lane segment (setup scan)
    float cpp = cp1;
    asm("s_nop 1\n\t"
        "v_mul_f32_dpp %0, %0, %0 row_shr:1 row_mask:0xf bank_mask:0xf\n\t"
        "s_nop 1\n\t"
        "v_mul_f32_dpp %0, %0, %0 row_shr:2 row_mask:0xf bank_mask:0xf\n\t"
        "s_nop 1\n\t"
        "v_mul_f32_dpp %0, %0, %0 row_shr:4 row_mask:0xf bank_mask:0xf\n\t"
        "s_nop 1\n\t"
        "v_mul_f32_dpp %0, %0, %0 row_shr:8 row_mask:0xf bank_mask:0xf"
        : "+v"(cpp));

    // odd deg-7 tanh poly on |x|<=1 (max err ~1.5e-4); sc, cpp, s1 folded:
    //   av = s0l + q*(qa + qb*y + qc*y^2 + qd*y^3),  y = q^2
    const float TAc = 0.999904f, TBc = -0.331065f,
                TCc = 0.120472f, TDc = -0.027717f;
    const float kk  = sc * cpp;
    const float k2  = kk * kk;
    const float qa  = act ? s1 * TAc * kk            : 0.f;
    const float qb  = act ? s1 * TBc * kk * k2       : 0.f;
    const float qc  = act ? s1 * TCc * kk * k2 * k2  : 0.f;
    const float qd  = act ? s1 * TDc * kk * k2 * k2 * k2 : 0.f;

    float hn = 0.f;      // normalized h[w] (valid in lanes 0..9)
    float cc = 0.f;      // c[w]
    float htr = 0.f;     // hterm / 2pi (revolution domain)

    // z stream comes from LDS: per-lane row gwl, contiguous in t.
    const int gwl = g * 10 + (act ? w : 9);
    const float* zb = Zl + (size_t)gwl * ZPAD;
    float4 zb0 = *(const float4*)(zb);
    float4 zb1 = *(const float4*)(zb + 4);

    // per-lane LDS base for the ys staging tile
    float* ysl = ys_l + lane;

    for (int gq = 0; gq < T_STEPS / 4; gq++) {
        float4 zc = zb0;
        zb0 = zb1;
        const int nl = (gq + 2 < T_STEPS / 4) ? gq + 2 : T_STEPS / 4 - 1;
        zb1 = *(const float4*)(zb + (size_t)nl * 4);

        float zs[4] = {zc.x, zc.y, zc.z, zc.w};
#pragma unroll
        for (int j = 0; j < 4; j++) {
            const int t = gq * 4 + j;

            // cos front: ONE add in revolution domain, then HW fract/cos
            float r = zs[j] + htr;
            float cv;
            asm("v_fract_f32 %0, %1\n\t"
                "v_cos_f32 %0, %0\n\t"
                "s_nop 1"
                : "=v"(cv) : "v"(r));

            // segmented inclusive cumprod directly on cos values
            // (cp1 prefix folded into poly coeffs). bound_ctrl off:
            // invalid lanes keep dest == mul-by-1.0 identity.
            float prod = cv;
            asm("s_nop 1\n\t"
                "v_mul_f32_dpp %0, %0, %0 row_shr:1 row_mask:0xf bank_mask:0xf\n\t"
                "s_nop 1\n\t"
                "v_mul_f32_dpp %0, %0, %0 row_shr:2 row_mask:0xf bank_mask:0xf\n\t"
                "s_nop 1\n\t"
                "v_mul_f32_dpp %0, %0, %0 row_shr:4 row_mask:0xf bank_mask:0xf\n\t"
                "s_nop 1\n\t"
                "v_mul_f32_dpp %0, %0, %0 row_shr:8 row_mask:0xf bank_mask:0xf"
                : "+v"(prod));

            // activation via folded odd poly, Estrin (depth 4 after prod)
            float y  = prod * prod;
            float t0 = fmaf(y, qb, qa);
            float t1 = fmaf(y, qd, qc);
            float y2 = y * y;
            float qp = fmaf(y2, t1, t0);
            float av = fmaf(prod, qp, s0l);

            // gather the 4 gates' activations for this lane's w (VALU permlanes)
            float a_ = av, b_ = av;
            asm("s_nop 1\n\t"
                "v_permlane32_swap_b32 %0, %1" : "+v"(a_), "+v"(b_));
            float F_ = a_, I_ = a_;   // F: f_w in all lanes, I: i_w in all lanes
            asm("s_nop 1\n\t"
                "v_permlane16_swap_b32 %0, %1" : "+v"(F_), "+v"(I_));
            float U_ = b_, O_ = b_;   // U: u_w, O: o_w
            asm("s_nop 1\n\t"
                "v_permlane16_swap_b32 %0, %1" : "+v"(U_), "+v"(O_));

            cc = fmaf(F_, cc, I_ * U_);

            // cc tanh: Pade [5/4] (|cc| <= 2.07), rcp-overlapped:
            // on = O_*num computes while rcp(den) is in flight;
            // hraw lands ONE hop after the rcp.
            float x2  = cc * cc;
            float num = cc * fmaf(x2, (x2 + 105.f), 945.f);
            float den = fmaf(x2, fmaf(x2, 15.f, 420.f), 945.f);
            float rd  = frcp(den);
            float on  = O_ * num;                  // parallel with rcp
            float hraw = fmaf(on, rd, hn);         // residual skip

            // LN stats: hraw==0 in lanes w>=10 by induction (coeffs zeroed).
            float v1 = hraw * 0.1f;
            float v2 = hraw * hraw;
            asm("s_nop 1\n\t"
                "v_add_f32_dpp %0, %0, %0 row_ror:8 row_mask:0xf bank_mask:0xf\n\t"
                "v_add_f32_dpp %1, %1, %1 row_ror:8 row_mask:0xf bank_mask:0xf\n\t"
                "s_nop 0\n\t"
                "v_add_f32_dpp %0, %0, %0 row_ror:4 row_mask:0xf bank_mask:0xf\n\t"
                "v_add_f32_dpp %1, %1, %1 row_ror:4 row_mask:0xf bank_mask:0xf\n\t"
                "s_nop 0\n\t"
                "v_add_f32_dpp %0, %0, %0 row_ror:2 row_mask:0xf bank_mask:0xf\n\t"
                "v_add_f32_dpp %1, %1, %1 row_ror:2 row_mask:0xf bank_mask:0xf\n\t"
                "s_nop 0\n\t"
                "v_add_f32_dpp %0, %0, %0 row_ror:1 row_mask:0xf bank_mask:0xf\n\t"
                "v_add_f32_dpp %1, %1, %1 row_ror:1 row_mask:0xf bank_mask:0xf"
                : "+v"(v1), "+v"(v2));

            // D = sum_j whp'[j]*hraw[j] via readlane (overlaps the DPP reduce)
            float d0 = whp[0] * rdlane(hraw, 0);
            float d1 = whp[1] * rdlane(hraw, 1);
            d0 = fmaf(whp[2], rdlane(hraw, 2), d0);
            d1 = fmaf(whp[3], rdlane(hraw, 3), d1);
            d0 = fmaf(whp[4], rdlane(hraw, 4), d0);
            d1 = fmaf(whp[5], rdlane(hraw, 5), d1);
            d0 = fmaf(whp[6], rdlane(hraw, 6), d0);
            d1 = fmaf(whp[7], rdlane(hraw, 7), d1);
            d0 = fmaf(whp[8], rdlane(hraw, 8), d0);
            d1 = fmaf(whp[9], rdlane(hraw, 9), d1);
            float D = d0 + d1;

            // LN tail: mu = v1; var = 0.1*v2 - mu^2 (+eps), folded fmas
            float mu   = v1;
            float rstd = __builtin_amdgcn_rsqf(
                             fmaf(v2, 0.1f, fmaf(-mu, mu, 1e-5f)));
            float hc   = hraw - mu;               // ready before rstd lands

            hn  = fmaf(hc * rstd, lng, lnb);      // off the critical path
            htr = fmaf(rstd, fmaf(-mu, S, D), A); // revolution domain

            // stage to LDS, all 64 lanes (lanes >= 10 pre-write future slots
            // that valid writes overwrite in order; spill lands in the pad)
            ysl[t * H_SZ] = hn;
        }
    }

    // ---- epilogue: bulk dump ys_l -> global (pipelined, off the chain) -----
#pragma unroll
    for (int k = 0; k < 20; k++) {
        int idx = k * 64 + lane;           // 0..1279
        int t   = idx / H_SZ;
        int ww  = idx - t * H_SZ;
        ys[(size_t)t * B_SZ * H_SZ + (size_t)b * H_SZ + ww] = ys_l[idx];
    }

    if (lane < H_SZ) {
        outH[b * H_SZ + lane] = hn;
        outC[b * H_SZ + lane] = cc;
    }
}

extern "C" void kernel_launch(void* const* d_in, const int* in_sizes, int n_in,
                              void* d_out, int out_size, void* d_ws, size_t ws_size,
                              hipStream_t stream)
{
    const float* x    = (const float*)d_in[0];
    const float* Wf   = (const float*)d_in[1];
    const float* bf   = (const float*)d_in[2];
    const float* pf   = (const float*)d_in[3];
    const float* Wi   = (const float*)d_in[4];
    const float* bi   = (const float*)d_in[5];
    const float* pi   = (const float*)d_in[6];
    const float* Wu   = (const float*)d_in[7];
    const float* bu   = (const float*)d_in[8];
    const float* pu   = (const float*)d_in[9];
    const float* Wo   = (const float*)d_in[10];
    const float* bo   = (const float*)d_in[11];
    const float* po   = (const float*)d_in[12];
    const float* ln_g = (const float*)d_in[13];
    const float* ln_b = (const float*)d_in[14];

    float* ys   = (float*)d_out;              // (T,B,H)
    float* outH = ys + (size_t)T_STEPS * B_SZ * H_SZ;
    float* outC = outH + (size_t)B_SZ * H_SZ;

    qlstm_fused<<<B_SZ, 1024, 0, stream>>>(
        x, Wf, bf, pf, Wi, bi, pi, Wu, bu, pu, Wo, bo, po,
        ln_g, ln_b, ys, outH, outC);
}

// Round 12
// 117.606 us; speedup vs baseline: 1.0228x; 1.0228x over previous
//
#include <hip/hip_runtime.h>
#include <math.h>

// QLSTM fused single-kernel version.
//
// qgate(x,p)[b,w] = prod_{j<=w} cos(p[j,1]) * cos(p[j,0] + x[b,j])
//
// Round 17 (this session): recombine best components. R16's 1024-thread
// gw-split regressed vs R15 (16-wave launch/drain + 8x redundant x-loads
// outweighed the phase-1 issue savings on an already-sub-2us phase).
// This round: R15's proven phase-1 d-split (256 threads, best dur 119.2)
// + R16's two orthogonal chain-depth trims:
//   (a) Estrin gate poly: depth 4 vs 5 after prod.
//   (b) cc-tanh rcp overlap: on = O_*num during rcp(den) flight; hraw
//       lands one hop after the rcp.
// Recurrence otherwise identical to R15.

#define T_STEPS 128
#define B_SZ    256
#define D_IN    64
#define H_SZ    10
#define COMB    74   // D_IN + H_SZ
#define ZPAD    132  // Z row stride (floats); 132*4=528 B keeps b128 16B-aligned

#define INV2PI  0.15915494f

__device__ __forceinline__ float rdlane(float v, int lane) {
    return __int_as_float(__builtin_amdgcn_readlane(__float_as_int(v), lane));
}
__device__ __forceinline__ float frcp(float x) { return __builtin_amdgcn_rcpf(x); }

__global__ __launch_bounds__(256) void qlstm_fused(
    const float* __restrict__ x,
    const float* __restrict__ Wf, const float* __restrict__ bf, const float* __restrict__ pf,
    const float* __restrict__ Wi, const float* __restrict__ bi, const float* __restrict__ pi,
    const float* __restrict__ Wu, const float* __restrict__ bu, const float* __restrict__ pu,
    const float* __restrict__ Wo, const float* __restrict__ bo, const float* __restrict__ po,
    const float* __restrict__ ln_g, const float* __restrict__ ln_b,
    float* __restrict__ ys, float* __restrict__ outH, float* __restrict__ outC)
{
    __shared__ __align__(16) float Wl[40 * 64];              // 10.0 KB
    __shared__ __align__(16) float Zl[40 * ZPAD];            // 21.1 KB
    __shared__ __align__(16) float Ztmp[40 * 128];           // 20.0 KB partials
    __shared__ __align__(16) float ys_l[T_STEPS * H_SZ + 64]; // 5.4 KB
    __shared__ float bl[40];
    __shared__ float p0l[40];
    // total ~57.6 KB < 64 KB static limit

    const int tid = threadIdx.x;   // 0..255
    const int bs  = tid >> 7;      // row-half selector (0: d 0-31, 1: d 32-63)
    const int tt  = tid & 127;     // t-row owner in phase 1
    const int b   = blockIdx.x;    // batch

    // ---- phase 0: half x-row (32 floats) into regs -------------------------
    float xr[32];
    const float4* xin = (const float4*)(x + ((size_t)tt * B_SZ + b) * D_IN + bs * 32);
#pragma unroll
    for (int k = 0; k < 8; k++) {
        float4 v = xin[k];
        xr[4*k+0] = v.x; xr[4*k+1] = v.y; xr[4*k+2] = v.z; xr[4*k+3] = v.w;
    }

    // ---- stage W,b,p0 into LDS (r wave-uniform -> scalar branches) ---------
#pragma unroll
    for (int k = 0; k < 10; k++) {
        int idx = k * 256 + tid;
        int r   = idx >> 6;        // row 0..39, uniform within each wave
        int col = idx & 63;
        const float* Wp; int w;
        if      (r < 10) { Wp = Wf; w = r;      }
        else if (r < 20) { Wp = Wi; w = r - 10; }
        else if (r < 30) { Wp = Wu; w = r - 20; }
        else             { Wp = Wo; w = r - 30; }
        Wl[idx] = Wp[w * COMB + col];
    }
    if (tid < 40) {
        int r = tid;
        const float* bp; const float* pp; int w;
        if      (r < 10) { bp = bf; pp = pf; w = r;      }
        else if (r < 20) { bp = bi; pp = pi; w = r - 10; }
        else if (r < 30) { bp = bu; pp = pu; w = r - 20; }
        else             { bp = bo; pp = po; w = r - 30; }
        bl[tid]  = bp[w];
        p0l[tid] = pp[w * 3];
    }
    __syncthreads();

    // ---- phase 1: half-dots; bs=1 stages partials; bs=0 combines -----------
    float acc[40];
#pragma unroll
    for (int gw = 0; gw < 40; gw++) {
        float a = bs ? 0.f : bl[gw];
        const float4* wr4 = (const float4*)(Wl + gw * 64 + bs * 32); // uniform
#pragma unroll
        for (int d4 = 0; d4 < 8; d4++) {
            float4 wv = wr4[d4];
            a = fmaf(xr[4*d4+0], wv.x, a);
            a = fmaf(xr[4*d4+1], wv.y, a);
            a = fmaf(xr[4*d4+2], wv.z, a);
            a = fmaf(xr[4*d4+3], wv.w, a);
        }
        acc[gw] = a;
    }
    if (bs) {
#pragma unroll
        for (int gw = 0; gw < 40; gw++)
            Ztmp[gw * 128 + tt] = acc[gw];          // stride-1 lanes: no conflict
    }
    __syncthreads();
    if (!bs) {
#pragma unroll
        for (int gw = 0; gw < 40; gw++)
            Zl[gw * ZPAD + tt] =
                (acc[gw] + Ztmp[gw * 128 + tt] + p0l[gw]) * INV2PI; // rev domain
    }
    __syncthreads();

    if (tid >= 64) return;         // waves 1-3 done; wave 0 runs the recurrence

    // ---- phase 2: sequential recurrence ------------------------------------
    const int lane = tid;
    const int g    = lane >> 4;        // gate 0..3 = f,i,u,o
    const int w    = lane & 15;        // wire 0..15 (10 active)
    const bool act = (w < H_SZ);

    const float* Ws[4] = {Wf, Wi, Wu, Wo};
    const float* ps[4] = {pf, pi, pu, po};

    // LN folded into the recurrence, REV-DOMAIN scaled:
    //   htr = hterm/2pi = rstd*(sum_j whp'[j]*hraw[j] - mu*S) + A
    float whp[H_SZ];
    float S = 0.f, A = 0.f;
#pragma unroll
    for (int j = 0; j < H_SZ; j++) {
        float whj = act ? Ws[g][w * COMB + D_IN + j] : 0.f;
        whp[j] = whj * ln_g[j] * INV2PI;
        S += whp[j];
        A  = fmaf(whj, ln_b[j], A);
    }
    A *= INV2PI;

    const float cp1 = act ? __cosf(ps[g][w * 3 + 1]) : 1.f;
    const float lng = act ? ln_g[w] : 0.f;
    const float lnb = act ? ln_b[w] : 0.f;
    // gate u (g==2): tanh(q); others: sigmoid(q) = 0.5 + 0.5*tanh(q/2)
    const float s1 = (g == 2) ? 1.f : 0.5f;
    const float sc = (g == 2) ? 1.f : 0.5f;
    const float s0l = (act ? ((g == 2) ? 0.f : 0.5f) : 0.f);

    // cpp = prefix product of cp1 within the 16-lane segment (setup scan)
    float cpp = cp1;
    asm("s_nop 1\n\t"
        "v_mul_f32_dpp %0, %0, %0 row_shr:1 row_mask:0xf bank_mask:0xf\n\t"
        "s_nop 1\n\t"
        "v_mul_f32_dpp %0, %0, %0 row_shr:2 row_mask:0xf bank_mask:0xf\n\t"
        "s_nop 1\n\t"
        "v_mul_f32_dpp %0, %0, %0 row_shr:4 row_mask:0xf bank_mask:0xf\n\t"
        "s_nop 1\n\t"
        "v_mul_f32_dpp %0, %0, %0 row_shr:8 row_mask:0xf bank_mask:0xf"
        : "+v"(cpp));

    // odd deg-7 tanh poly on |x|<=1 (max err ~1.5e-4); sc, cpp, s1 folded:
    //   av = s0l + q*(qa + qb*y + qc*y^2 + qd*y^3),  y = q^2
    const float TAc = 0.999904f, TBc = -0.331065f,
                TCc = 0.120472f, TDc = -0.027717f;
    const float kk  = sc * cpp;
    const float k2  = kk * kk;
    const float qa  = act ? s1 * TAc * kk            : 0.f;
    const float qb  = act ? s1 * TBc * kk * k2       : 0.f;
    const float qc  = act ? s1 * TCc * kk * k2 * k2  : 0.f;
    const float qd  = act ? s1 * TDc * kk * k2 * k2 * k2 : 0.f;

    float hn = 0.f;      // normalized h[w] (valid in lanes 0..9)
    float cc = 0.f;      // c[w]
    float htr = 0.f;     // hterm / 2pi (revolution domain)

    // z stream comes from LDS: per-lane row gwl, contiguous in t.
    const int gwl = g * 10 + (act ? w : 9);
    const float* zb = Zl + (size_t)gwl * ZPAD;
    float4 zb0 = *(const float4*)(zb);
    float4 zb1 = *(const float4*)(zb + 4);

    // per-lane LDS base for the ys staging tile
    float* ysl = ys_l + lane;

    for (int gq = 0; gq < T_STEPS / 4; gq++) {
        float4 zc = zb0;
        zb0 = zb1;
        const int nl = (gq + 2 < T_STEPS / 4) ? gq + 2 : T_STEPS / 4 - 1;
        zb1 = *(const float4*)(zb + (size_t)nl * 4);

        float zs[4] = {zc.x, zc.y, zc.z, zc.w};
#pragma unroll
        for (int j = 0; j < 4; j++) {
            const int t = gq * 4 + j;

            // cos front: ONE add in revolution domain, then HW fract/cos
            float r = zs[j] + htr;
            float cv;
            asm("v_fract_f32 %0, %1\n\t"
                "v_cos_f32 %0, %0\n\t"
                "s_nop 1"
                : "=v"(cv) : "v"(r));

            // segmented inclusive cumprod directly on cos values
            // (cp1 prefix folded into poly coeffs). bound_ctrl off:
            // invalid lanes keep dest == mul-by-1.0 identity.
            float prod = cv;
            asm("s_nop 1\n\t"
                "v_mul_f32_dpp %0, %0, %0 row_shr:1 row_mask:0xf bank_mask:0xf\n\t"
                "s_nop 1\n\t"
                "v_mul_f32_dpp %0, %0, %0 row_shr:2 row_mask:0xf bank_mask:0xf\n\t"
                "s_nop 1\n\t"
                "v_mul_f32_dpp %0, %0, %0 row_shr:4 row_mask:0xf bank_mask:0xf\n\t"
                "s_nop 1\n\t"
                "v_mul_f32_dpp %0, %0, %0 row_shr:8 row_mask:0xf bank_mask:0xf"
                : "+v"(prod));

            // activation via folded odd poly, Estrin (depth 4 after prod)
            float y  = prod * prod;
            float t0 = fmaf(y, qb, qa);
            float t1 = fmaf(y, qd, qc);
            float y2 = y * y;
            float qp = fmaf(y2, t1, t0);
            float av = fmaf(prod, qp, s0l);

            // gather the 4 gates' activations for this lane's w (VALU permlanes)
            float a_ = av, b_ = av;
            asm("s_nop 1\n\t"
                "v_permlane32_swap_b32 %0, %1" : "+v"(a_), "+v"(b_));
            float F_ = a_, I_ = a_;   // F: f_w in all lanes, I: i_w in all lanes
            asm("s_nop 1\n\t"
                "v_permlane16_swap_b32 %0, %1" : "+v"(F_), "+v"(I_));
            float U_ = b_, O_ = b_;   // U: u_w, O: o_w
            asm("s_nop 1\n\t"
                "v_permlane16_swap_b32 %0, %1" : "+v"(U_), "+v"(O_));

            cc = fmaf(F_, cc, I_ * U_);

            // cc tanh: Pade [5/4] (|cc| <= 2.07), rcp-overlapped:
            // on = O_*num computes while rcp(den) is in flight;
            // hraw lands ONE hop after the rcp.
            float x2  = cc * cc;
            float num = cc * fmaf(x2, (x2 + 105.f), 945.f);
            float den = fmaf(x2, fmaf(x2, 15.f, 420.f), 945.f);
            float rd  = frcp(den);
            float on  = O_ * num;                  // parallel with rcp
            float hraw = fmaf(on, rd, hn);         // residual skip

            // LN stats: hraw==0 in lanes w>=10 by induction (coeffs zeroed).
            // v1 and v2 both directly from hraw (parallel).
            float v1 = hraw * 0.1f;
            float v2 = hraw * hraw;
            asm("s_nop 1\n\t"
                "v_add_f32_dpp %0, %0, %0 row_ror:8 row_mask:0xf bank_mask:0xf\n\t"
                "v_add_f32_dpp %1, %1, %1 row_ror:8 row_mask:0xf bank_mask:0xf\n\t"
                "s_nop 0\n\t"
                "v_add_f32_dpp %0, %0, %0 row_ror:4 row_mask:0xf bank_mask:0xf\n\t"
                "v_add_f32_dpp %1, %1, %1 row_ror:4 row_mask:0xf bank_mask:0xf\n\t"
                "s_nop 0\n\t"
                "v_add_f32_dpp %0, %0, %0 row_ror:2 row_mask:0xf bank_mask:0xf\n\t"
                "v_add_f32_dpp %1, %1, %1 row_ror:2 row_mask:0xf bank_mask:0xf\n\t"
                "s_nop 0\n\t"
                "v_add_f32_dpp %0, %0, %0 row_ror:1 row_mask:0xf bank_mask:0xf\n\t"
                "v_add_f32_dpp %1, %1, %1 row_ror:1 row_mask:0xf bank_mask:0xf"
                : "+v"(v1), "+v"(v2));

            // D = sum_j whp'[j]*hraw[j] via readlane (overlaps the DPP reduce)
            float d0 = whp[0] * rdlane(hraw, 0);
            float d1 = whp[1] * rdlane(hraw, 1);
            d0 = fmaf(whp[2], rdlane(hraw, 2), d0);
            d1 = fmaf(whp[3], rdlane(hraw, 3), d1);
            d0 = fmaf(whp[4], rdlane(hraw, 4), d0);
            d1 = fmaf(whp[5], rdlane(hraw, 5), d1);
            d0 = fmaf(whp[6], rdlane(hraw, 6), d0);
            d1 = fmaf(whp[7], rdlane(hraw, 7), d1);
            d0 = fmaf(whp[8], rdlane(hraw, 8), d0);
            d1 = fmaf(whp[9], rdlane(hraw, 9), d1);
            float D = d0 + d1;

            // LN tail: mu = v1; var = 0.1*v2 - mu^2 (+eps), folded fmas
            float mu   = v1;
            float rstd = __builtin_amdgcn_rsqf(
                             fmaf(v2, 0.1f, fmaf(-mu, mu, 1e-5f)));
            float hc   = hraw - mu;               // ready before rstd lands

            hn  = fmaf(hc * rstd, lng, lnb);      // off the critical path
            htr = fmaf(rstd, fmaf(-mu, S, D), A); // revolution domain

            // stage to LDS, all 64 lanes (lanes >= 10 pre-write future slots
            // that valid writes overwrite in order; spill lands in the pad)
            ysl[t * H_SZ] = hn;
        }
    }

    // ---- epilogue: bulk dump ys_l -> global (pipelined, off the chain) -----
#pragma unroll
    for (int k = 0; k < 20; k++) {
        int idx = k * 64 + lane;           // 0..1279
        int t   = idx / H_SZ;
        int ww  = idx - t * H_SZ;
        ys[(size_t)t * B_SZ * H_SZ + (size_t)b * H_SZ + ww] = ys_l[idx];
    }

    if (lane < H_SZ) {
        outH[b * H_SZ + lane] = hn;
        outC[b * H_SZ + lane] = cc;
    }
}

extern "C" void kernel_launch(void* const* d_in, const int* in_sizes, int n_in,
                              void* d_out, int out_size, void* d_ws, size_t ws_size,
                              hipStream_t stream)
{
    const float* x    = (const float*)d_in[0];
    const float* Wf   = (const float*)d_in[1];
    const float* bf   = (const float*)d_in[2];
    const float* pf   = (const float*)d_in[3];
    const float* Wi   = (const float*)d_in[4];
    const float* bi   = (const float*)d_in[5];
    const float* pi   = (const float*)d_in[6];
    const float* Wu   = (const float*)d_in[7];
    const float* bu   = (const float*)d_in[8];
    const float* pu   = (const float*)d_in[9];
    const float* Wo   = (const float*)d_in[10];
    const float* bo   = (const float*)d_in[11];
    const float* po   = (const float*)d_in[12];
    const float* ln_g = (const float*)d_in[13];
    const float* ln_b = (const float*)d_in[14];

    float* ys   = (float*)d_out;              // (T,B,H)
    float* outH = ys + (size_t)T_STEPS * B_SZ * H_SZ;
    float* outC = outH + (size_t)B_SZ * H_SZ;

    qlstm_fused<<<B_SZ, 256, 0, stream>>>(
        x, Wf, bf, pf, Wi, bi, pi, Wu, bu, pu, Wo, bo, po,
        ln_g, ln_b, ys, outH, outC);
}